// Round 10
// baseline (150.097 us; speedup 1.0000x reference)
//
#include <hip/hip_runtime.h>
#include <math.h>

// Problem constants (from reference)
#define Bdim 32
#define Ndim 325
#define Kdim 20
#define Sdim 12      // S_IN == S_OUT == 12
#define Cdim 10
#define Hdim 48      // 4*S_OUT
#define NB   (Bdim*Ndim)                  // 10400 (b,n) pairs
#define OUT_SCALARS (NB*Cdim*Sdim)        // output_data floats, then 3 scalars
#define Tpairs (Kdim*(Kdim-1)/2)          // 190 upper-triangle pairs
#define BN_BLOCKS (NB/4)                  // 2600 blocks (4 bn each)

// Workspace layout (float offsets) — only partials now
#define O_PCL 0                           // BN_BLOCKS cluster-loss partials
#define O_PDS (O_PCL + BN_BLOCKS)         // BN_BLOCKS dist-sum partials
#define O_PWH (O_PDS + BN_BLOCKS)         // 1 wh-sum (written by mega block 0)
#define WS_BASE_FLOATS (O_PWH + 4)

__device__ __forceinline__ float leaky(float x) { return x >= 0.f ? x : 0.5f * x; }

// ---------------------------------------------------------------------------
// K1 (everything): 4 bn per 256-thread block, 2600 blocks.
// Phase 0: stage ALL weights to LDS (1848 floats; 459 float4 + b2 scalars).
// Phase 1: lanes 0..83 compute wh for 80 gathered neighbors + 4 self nodes
//          directly from x (144 FMA each; wW via LDS broadcast).
// Phase 2: lanes 0..191 compute hx(+b1) for the 4 bn; lanes 192..255 compute
//          the 80 invn factors + diagonal dist terms (order-free: all loss
//          contributions land in the same block partial).
// Phase 3: lanes 0..159, 2 lanes/edge: hy computed INLINE from s_whj
//          (12 FMA/d, LDS broadcast), hidden->logits->shfl_xor->softmax.
// Phase 4: per-slot einsum (t<30) + 190-pair symmetric loss; block partials.
// Block 0 extra duty: wh.mean() partial over all NB nodes (hidden under grid).
// No fences / global atomics (R4 lesson).
// ---------------------------------------------------------------------------
__global__ __launch_bounds__(256)
void mega_kernel(const float* __restrict__ x,
                 const float* __restrict__ wW, const float* __restrict__ wb,
                 const float* __restrict__ A1, const float* __restrict__ b1,
                 const float* __restrict__ A2, const float* __restrict__ b2,
                 const int*   __restrict__ topk,
                 float* __restrict__ ws, float* __restrict__ out)
{
    __shared__ __attribute__((aligned(16))) float s_A1[2 * Sdim * Hdim]; // 1152
    __shared__ __attribute__((aligned(16))) float s_A2[Hdim * Cdim];     // 480
    __shared__ __attribute__((aligned(16))) float s_wW[Sdim * Sdim];     // 144
    __shared__ __attribute__((aligned(16))) float s_b1[Hdim];            // 48
    __shared__ __attribute__((aligned(16))) float s_wb[Sdim];            // 12
    __shared__ __attribute__((aligned(16))) float s_b2[12];
    __shared__ __attribute__((aligned(16))) float s_whs[4][Sdim];        // self wh
    __shared__ __attribute__((aligned(16))) float s_hx [4][Hdim];        // hx + b1
    __shared__ __attribute__((aligned(16))) float s_whj[4][Kdim][12];
    __shared__ __attribute__((aligned(16))) float s_am [4][Kdim][12];
    __shared__ __attribute__((aligned(16))) float s_invn[4][Kdim];
    __shared__ float s_red[2][4];
    __shared__ float s_red2[4];

    const int tid = threadIdx.x;
    const int slot = tid >> 6, t = tid & 63;

    // ---- phase 0: stage weights (459 float4 sections + b2) ----
    {
        const float4* A1_4 = (const float4*)A1;
        const float4* A2_4 = (const float4*)A2;
        const float4* wW_4 = (const float4*)wW;
        const float4* b1_4 = (const float4*)b1;
        const float4* wb_4 = (const float4*)wb;
        for (int i = tid; i < 459; i += 256) {
            if (i < 288)      *(float4*)&s_A1[i * 4]         = A1_4[i];
            else if (i < 408) *(float4*)&s_A2[(i - 288) * 4] = A2_4[i - 288];
            else if (i < 444) *(float4*)&s_wW[(i - 408) * 4] = wW_4[i - 408];
            else if (i < 456) *(float4*)&s_b1[(i - 444) * 4] = b1_4[i - 444];
            else              *(float4*)&s_wb[(i - 456) * 4] = wb_4[i - 456];
        }
        if (tid < Cdim) s_b2[tid] = b2[tid];
    }
    __syncthreads();

    // ---- phase 1: wh for 80 neighbors + 4 self ----
    if (tid < 84) {
        int sl, k = 0;
        const float* xr;
        if (tid < 80) {
            sl = tid / 20; k = tid - sl * 20;
            const int bn_e = blockIdx.x * 4 + sl;
            const int b_e  = bn_e / Ndim;
            const int j    = topk[(size_t)blockIdx.x * 80 + tid];
            xr = x + ((size_t)b_e * Ndim + j) * Sdim;
        } else {
            sl = tid - 80;
            xr = x + (size_t)(blockIdx.x * 4 + sl) * Sdim;
        }
        const float4 x0 = ((const float4*)xr)[0];
        const float4 x1 = ((const float4*)xr)[1];
        const float4 x2 = ((const float4*)xr)[2];
        const float xs[12] = { x0.x,x0.y,x0.z,x0.w, x1.x,x1.y,x1.z,x1.w, x2.x,x2.y,x2.z,x2.w };
        float wh[12];
        #pragma unroll
        for (int s = 0; s < Sdim; s++) {
            float acc = s_wb[s];
            #pragma unroll
            for (int i = 0; i < Sdim; i++) acc += xs[i] * s_wW[i * Sdim + s];
            wh[s] = leaky(acc);
        }
        float* dst = (tid < 80) ? &s_whj[sl][k][0] : &s_whs[sl][0];
        ((float4*)dst)[0] = make_float4(wh[0], wh[1], wh[2],  wh[3]);
        ((float4*)dst)[1] = make_float4(wh[4], wh[5], wh[6],  wh[7]);
        ((float4*)dst)[2] = make_float4(wh[8], wh[9], wh[10], wh[11]);
    }
    __syncthreads();

    float cl = 0.f, ds = 0.f;

    // ---- phase 2: hx(+b1) for 4 bn (lanes 0..191) || invn (lanes 192..255) ----
    if (tid < 192) {
        const int sl = tid / Hdim, d = tid - sl * Hdim;
        float acc = s_b1[d];
        #pragma unroll
        for (int s = 0; s < Sdim; s++) acc += s_whs[sl][s] * s_A1[s * Hdim + d];
        s_hx[sl][d] = acc;
    } else {
        for (int i = tid - 192; i < 80; i += 64) {
            const int sl = i / 20, k = i - sl * 20;
            const float4 w0 = *(const float4*)&s_whj[sl][k][0];
            const float4 w1 = *(const float4*)&s_whj[sl][k][4];
            const float4 w2 = *(const float4*)&s_whj[sl][k][8];
            const float nn = w0.x*w0.x + w0.y*w0.y + w0.z*w0.z + w0.w*w0.w
                           + w1.x*w1.x + w1.y*w1.y + w1.z*w1.z + w1.w*w1.w
                           + w2.x*w2.x + w2.y*w2.y + w2.z*w2.z + w2.w*w2.w;
            const float invn = 1.f / (sqrtf(nn) + 1e-8f);
            s_invn[sl][k] = invn;
            ds += nn * invn * invn;           // dist_mat diagonal (any lane is fine)
        }
    }
    __syncthreads();

    // ---- phase 3: edge logits, 2 lanes/edge, hy inline from s_whj ----
    if (tid < 160) {
        const int e = tid >> 1, half = tid & 1;
        const int sl = e / 20, kk = e - sl * 20;
        const float4 w0 = *(const float4*)&s_whj[sl][kk][0];
        const float4 w1 = *(const float4*)&s_whj[sl][kk][4];
        const float4 w2 = *(const float4*)&s_whj[sl][kk][8];
        const float w[12] = { w0.x,w0.y,w0.z,w0.w, w1.x,w1.y,w1.z,w1.w, w2.x,w2.y,w2.z,w2.w };

        float acc[Cdim];
        #pragma unroll
        for (int c = 0; c < Cdim; c++) acc[c] = 0.f;
        #pragma unroll
        for (int dd = 0; dd < 24; dd++) {
            const int d = half * 24 + dd;
            float hy = 0.f;
            #pragma unroll
            for (int s = 0; s < Sdim; s++) hy += w[s] * s_A1[(Sdim + s) * Hdim + d];
            const float h = leaky(s_hx[sl][d] + hy);
            #pragma unroll
            for (int c = 0; c < Cdim; c++) acc[c] += h * s_A2[d * Cdim + c];
        }
        float full[Cdim];
        #pragma unroll
        for (int c = 0; c < Cdim; c++) full[c] = acc[c] + __shfl_xor(acc[c], 1);
        if (half == 0) {
            float m = -1e30f;
            #pragma unroll
            for (int c = 0; c < Cdim; c++) { full[c] = leaky(full[c] + s_b2[c]); m = fmaxf(m, full[c]); }
            float sum = 0.f;
            #pragma unroll
            for (int c = 0; c < Cdim; c++) { full[c] = __expf(full[c] - m); sum += full[c]; }
            const float inv = 1.f / sum;
            *(float4*)&s_am[sl][kk][0] = make_float4(full[0]*inv, full[1]*inv, full[2]*inv, full[3]*inv);
            *(float4*)&s_am[sl][kk][4] = make_float4(full[4]*inv, full[5]*inv, full[6]*inv, full[7]*inv);
            *(float4*)&s_am[sl][kk][8] = make_float4(full[8]*inv, full[9]*inv, 0.f, 0.f);
        }
    }
    __syncthreads();

    const int bn = blockIdx.x * 4 + slot;

    // ---- phase 4a: output einsum (30 lanes per slot-wave) ----
    if (t < 30) {
        const int c = t / 3, sq = t - c * 3;
        float4 o = make_float4(0.f, 0.f, 0.f, 0.f);
        #pragma unroll
        for (int k = 0; k < Kdim; k++) {
            const float a = s_am[slot][k][c];
            const float4 wv = *(const float4*)&s_whj[slot][k][sq * 4];
            o.x += a * wv.x; o.y += a * wv.y; o.z += a * wv.z; o.w += a * wv.w;
        }
        *(float4*)(out + (size_t)bn * (Cdim * Sdim) + c * Sdim + sq * 4) = o;
    }

    // ---- phase 4b: 190 upper-triangle pairs, doubled (symmetric) ----
    #pragma unroll
    for (int it = 0; it < 3; it++) {
        const int e = t + it * 64;
        if (e < Tpairs) {
            const int r = Tpairs - 1 - e;
            const int m = (int)((sqrtf((float)(8 * r + 1)) - 1.f) * 0.5f + 1e-4f);
            const int k = Kdim - 2 - m;
            const int l = Kdim - 1 - (r - (m * (m + 1)) / 2);

            const float4 a0 = *(const float4*)&s_whj[slot][k][0];
            const float4 a1 = *(const float4*)&s_whj[slot][k][4];
            const float4 a2 = *(const float4*)&s_whj[slot][k][8];
            const float4 c0 = *(const float4*)&s_whj[slot][l][0];
            const float4 c1 = *(const float4*)&s_whj[slot][l][4];
            const float4 c2 = *(const float4*)&s_whj[slot][l][8];
            const float draw = a0.x*c0.x + a0.y*c0.y + a0.z*c0.z + a0.w*c0.w
                             + a1.x*c1.x + a1.y*c1.y + a1.z*c1.z + a1.w*c1.w
                             + a2.x*c2.x + a2.y*c2.y + a2.z*c2.z + a2.w*c2.w;
            const float d = draw * s_invn[slot][k] * s_invn[slot][l];

            const float4 p0 = *(const float4*)&s_am[slot][k][0];
            const float4 p1 = *(const float4*)&s_am[slot][k][4];
            const float4 p2 = *(const float4*)&s_am[slot][k][8];
            const float4 q0 = *(const float4*)&s_am[slot][l][0];
            const float4 q1 = *(const float4*)&s_am[slot][l][4];
            const float4 q2 = *(const float4*)&s_am[slot][l][8];
            float p = p0.x*q0.x + p0.y*q0.y + p0.z*q0.z + p0.w*q0.w
                    + p1.x*q1.x + p1.y*q1.y + p1.z*q1.z + p1.w*q1.w
                    + p2.x*q2.x + p2.y*q2.y + p2.z*q2.z + p2.w*q2.w;

            p = fminf(fmaxf(p, 1e-4f), 1.f - 1e-4f);
            const float lp = __logf(p);
            ds += 2.f * d;
            cl += 2.f * ((d >= 0.5f) ? -lp : lp);
        }
    }

    // wave reduce, cross-slot reduce -> block partial (plain stores)
    #pragma unroll
    for (int off = 32; off > 0; off >>= 1) {
        cl += __shfl_down(cl, off);
        ds += __shfl_down(ds, off);
    }
    if (t == 0) { s_red[0][slot] = cl; s_red[1][slot] = ds; }
    __syncthreads();
    if (tid == 0) {
        ws[O_PCL + blockIdx.x] = s_red[0][0] + s_red[0][1] + s_red[0][2] + s_red[0][3];
        ws[O_PDS + blockIdx.x] = s_red[1][0] + s_red[1][1] + s_red[1][2] + s_red[1][3];
    }

    // ---- block 0 extra duty: wh.mean() partial over all NB nodes ----
    if (blockIdx.x == 0) {
        float wm = 0.f;
        for (int node = tid; node < NB; node += 256) {
            const float* xr = x + (size_t)node * Sdim;
            const float4 x0 = ((const float4*)xr)[0];
            const float4 x1 = ((const float4*)xr)[1];
            const float4 x2 = ((const float4*)xr)[2];
            const float xs[12] = { x0.x,x0.y,x0.z,x0.w, x1.x,x1.y,x1.z,x1.w, x2.x,x2.y,x2.z,x2.w };
            #pragma unroll
            for (int s = 0; s < Sdim; s++) {
                float acc = s_wb[s];
                #pragma unroll
                for (int i = 0; i < Sdim; i++) acc += xs[i] * s_wW[i * Sdim + s];
                wm += leaky(acc);
            }
        }
        #pragma unroll
        for (int off = 32; off > 0; off >>= 1) wm += __shfl_down(wm, off);
        if (t == 0) s_red2[slot] = wm;
        __syncthreads();
        if (tid == 0) ws[O_PWH] = s_red2[0] + s_red2[1] + s_red2[2] + s_red2[3];
    }
}

// ---------------------------------------------------------------------------
// K2: reduce partials -> 3 output scalars (tiny)
// ---------------------------------------------------------------------------
__global__ __launch_bounds__(1024)
void finalize(const float* __restrict__ ws, float* __restrict__ out)
{
    const int t = threadIdx.x;
    float cl = 0.f, ds = 0.f;
    float wm = (t == 0) ? ws[O_PWH] : 0.f;
    for (int i = t; i < BN_BLOCKS; i += 1024) {
        cl += ws[O_PCL + i]; ds += ws[O_PDS + i];
    }
    #pragma unroll
    for (int off = 32; off > 0; off >>= 1) {
        cl += __shfl_down(cl, off);
        ds += __shfl_down(ds, off);
        wm += __shfl_down(wm, off);
    }
    __shared__ float r[3][16];
    const int w = t >> 6, lane = t & 63;
    if (lane == 0) { r[0][w] = cl; r[1][w] = ds; r[2][w] = wm; }
    __syncthreads();
    if (t == 0) {
        float c = 0.f, d = 0.f, m = 0.f;
        #pragma unroll
        for (int i = 0; i < 16; i++) { c += r[0][i]; d += r[1][i]; m += r[2][i]; }
        out[OUT_SCALARS + 0] = c * (1.f / (float)NB);
        out[OUT_SCALARS + 1] = d * (1.f / ((float)NB * Kdim * Kdim));
        out[OUT_SCALARS + 2] = m * (1.f / ((float)NB * Sdim));
    }
}

// ---------------------------------------------------------------------------
// Fallback: round-1 monolithic kernel (used only if ws is too small)
// ---------------------------------------------------------------------------
__global__ void zero_scalars(float* out) {
    const int t = threadIdx.x;
    if (t < 3) out[OUT_SCALARS + t] = 0.f;
}

__global__ __launch_bounds__(64)
void fused_kernel(const float* __restrict__ input_data,
                  const float* __restrict__ w_W,  const float* __restrict__ w_b,
                  const float* __restrict__ a1_W, const float* __restrict__ a1_b,
                  const float* __restrict__ a2_W, const float* __restrict__ a2_b,
                  const int*   __restrict__ topk,
                  float* __restrict__ out)
{
    __shared__ float s_wW[Sdim * Sdim];
    __shared__ float s_wb[Sdim];
    __shared__ float s_A1[2 * Sdim * Hdim];
    __shared__ float s_b1[Hdim];
    __shared__ float s_A2f[Hdim * Cdim];
    __shared__ float s_b2f[Cdim];
    __shared__ float s_whs[Sdim];
    __shared__ float s_hx[Hdim];
    __shared__ float s_whj[Kdim][Sdim + 1];
    __shared__ float s_hid[Kdim][Hdim + 1];
    __shared__ float s_am [Kdim][Cdim + 1];
    __shared__ float s_wtn[Kdim][Sdim + 1];
    __shared__ int   s_idx[Kdim];

    const int t = threadIdx.x, bn = blockIdx.x, b = bn / Ndim;

    for (int i = t; i < Sdim * Sdim; i += 64)      s_wW[i] = w_W[i];
    if (t < Sdim)                                  s_wb[t] = w_b[t];
    for (int i = t; i < 2 * Sdim * Hdim; i += 64)  s_A1[i] = a1_W[i];
    if (t < Hdim)                                  s_b1[t] = a1_b[t];
    for (int i = t; i < Hdim * Cdim; i += 64)      s_A2f[i] = a2_W[i];
    if (t < Cdim)                                  s_b2f[t] = a2_b[t];
    if (t < Kdim)                                  s_idx[t] = topk[(size_t)bn * Kdim + t];
    __syncthreads();

    const float* xs = input_data + (size_t)bn * Sdim;
    if (t < Sdim) {
        float acc = s_wb[t];
        #pragma unroll
        for (int i = 0; i < Sdim; i++) acc += xs[i] * s_wW[i * Sdim + t];
        s_whs[t] = leaky(acc);
    }
    __syncthreads();

    if (t < Hdim) {
        float acc = 0.f;
        #pragma unroll
        for (int s = 0; s < Sdim; s++) acc += s_whs[s] * s_A1[s * Hdim + t];
        s_hx[t] = acc;
    }
    for (int e = t; e < Kdim * Sdim; e += 64) {
        const int k = e / Sdim, ss = e - k * Sdim;
        const float* xj = input_data + ((size_t)b * Ndim + s_idx[k]) * Sdim;
        float acc = s_wb[ss];
        #pragma unroll
        for (int i = 0; i < Sdim; i++) acc += xj[i] * s_wW[i * Sdim + ss];
        s_whj[k][ss] = leaky(acc);
    }
    __syncthreads();

    for (int e = t; e < Kdim * Hdim; e += 64) {
        const int k = e / Hdim, d = e - k * Hdim;
        float acc = s_hx[d] + s_b1[d];
        #pragma unroll
        for (int s = 0; s < Sdim; s++) acc += s_whj[k][s] * s_A1[(Sdim + s) * Hdim + d];
        s_hid[k][d] = leaky(acc);
    }
    __syncthreads();

    for (int e = t; e < Kdim * Cdim; e += 64) {
        const int k = e / Cdim, c = e - k * Cdim;
        float acc = s_b2f[c];
        #pragma unroll
        for (int d = 0; d < Hdim; d++) acc += s_hid[k][d] * s_A2f[d * Cdim + c];
        s_am[k][c] = leaky(acc);
    }
    __syncthreads();

    if (t < Kdim) {
        float m = -1e30f;
        #pragma unroll
        for (int c = 0; c < Cdim; c++) m = fmaxf(m, s_am[t][c]);
        float ex[Cdim]; float sum = 0.f;
        #pragma unroll
        for (int c = 0; c < Cdim; c++) { ex[c] = expf(s_am[t][c] - m); sum += ex[c]; }
        const float inv = 1.f / sum;
        #pragma unroll
        for (int c = 0; c < Cdim; c++) s_am[t][c] = ex[c] * inv;
        float nn = 0.f;
        #pragma unroll
        for (int s = 0; s < Sdim; s++) nn += s_whj[t][s] * s_whj[t][s];
        const float invn = 1.f / (sqrtf(nn) + 1e-8f);
        #pragma unroll
        for (int s = 0; s < Sdim; s++) s_wtn[t][s] = s_whj[t][s] * invn;
    }
    __syncthreads();

    float* op = out + (size_t)bn * (Cdim * Sdim);
    for (int e = t; e < Cdim * Sdim; e += 64) {
        const int c = e / Sdim, ss = e - c * Sdim;
        float acc = 0.f;
        #pragma unroll
        for (int k = 0; k < Kdim; k++) acc += s_am[k][c] * s_whj[k][ss];
        op[e] = acc;
    }

    float cl = 0.f, ds = 0.f;
    for (int e = t; e < Kdim * Kdim; e += 64) {
        const int k = e / Kdim, l = e - k * Kdim;
        float d = 0.f;
        #pragma unroll
        for (int s = 0; s < Sdim; s++) d += s_wtn[k][s] * s_wtn[l][s];
        ds += d;
        if (k != l) {
            float p = 0.f;
            #pragma unroll
            for (int c = 0; c < Cdim; c++) p += s_am[k][c] * s_am[l][c];
            p = fminf(fmaxf(p, 1e-4f), 1.f - 1e-4f);
            const float lp = logf(p);
            cl += (d >= 0.5f) ? -lp : lp;
        }
    }
    float whl = (t < Sdim) ? s_whs[t] : 0.f;
    #pragma unroll
    for (int off = 32; off > 0; off >>= 1) {
        cl  += __shfl_down(cl,  off);
        ds  += __shfl_down(ds,  off);
        whl += __shfl_down(whl, off);
    }
    if (t == 0) {
        atomicAdd(&out[OUT_SCALARS + 0], cl  * (1.f / (float)NB));
        atomicAdd(&out[OUT_SCALARS + 1], ds  * (1.f / ((float)NB * Kdim * Kdim)));
        atomicAdd(&out[OUT_SCALARS + 2], whl * (1.f / ((float)NB * Sdim)));
    }
}

extern "C" void kernel_launch(void* const* d_in, const int* in_sizes, int n_in,
                              void* d_out, int out_size, void* d_ws, size_t ws_size,
                              hipStream_t stream) {
    (void)in_sizes; (void)n_in; (void)out_size;
    // 0=fushed_features(unused), 1=input_data, 2=w_W, 3=w_b, 4=a1_W, 5=a1_b,
    // 6=a2_W, 7=a2_b, 8=adj_mx_topk_index
    const float* input_data = (const float*)d_in[1];
    const float* w_W  = (const float*)d_in[2];
    const float* w_b  = (const float*)d_in[3];
    const float* a1_W = (const float*)d_in[4];
    const float* a1_b = (const float*)d_in[5];
    const float* a2_W = (const float*)d_in[6];
    const float* a2_b = (const float*)d_in[7];
    const int*   topk = (const int*)d_in[8];
    float* out = (float*)d_out;
    float* ws  = (float*)d_ws;

    if (ws_size >= (size_t)WS_BASE_FLOATS * sizeof(float)) {
        hipLaunchKernelGGL(mega_kernel, dim3(BN_BLOCKS), dim3(256), 0, stream,
                           input_data, w_W, w_b, a1_W, a1_b, a2_W, a2_b, topk, ws, out);
        hipLaunchKernelGGL(finalize, dim3(1), dim3(1024), 0, stream, ws, out);
    } else {
        hipLaunchKernelGGL(zero_scalars, dim3(1), dim3(64), 0, stream, out);
        hipLaunchKernelGGL(fused_kernel, dim3(NB), dim3(64), 0, stream,
                           input_data, w_W, w_b, a1_W, a1_b, a2_W, a2_b, topk, out);
    }
}

// Round 11
// 103.693 us; speedup vs baseline: 1.4475x; 1.4475x over previous
//
#include <hip/hip_runtime.h>
#include <math.h>

// Problem constants (from reference)
#define Bdim 32
#define Ndim 325
#define Kdim 20
#define Sdim 12      // S_IN == S_OUT == 12
#define Cdim 10
#define Hdim 48      // 4*S_OUT
#define NB   (Bdim*Ndim)                  // 10400 (b,n) pairs
#define OUT_SCALARS (NB*Cdim*Sdim)        // output_data floats, then 3 scalars
#define Tpairs (Kdim*(Kdim-1)/2)          // 190 upper-triangle pairs
#define BN_BLOCKS (NB/4)                  // 2600 blocks (4 bn each)
#define NODE_BLOCKS 260                   // 40 nodes per block
#define NPB 40

// Workspace layout (float offsets); all blocks 16B-aligned
#define O_WH  0                           // NB*12 node features wh
#define O_HX  (O_WH + NB*Sdim)            // NB*48: hx + a1_b (bias pre-folded)
#define O_HY  (O_HX + NB*Hdim)            // NB*48: hy
#define O_PCL (O_HY + NB*Hdim)            // BN_BLOCKS cluster-loss partials
#define O_PDS (O_PCL + BN_BLOCKS)         // BN_BLOCKS dist-sum partials
#define O_PWH (O_PDS + BN_BLOCKS)         // NODE_BLOCKS wh-sum partials
#define WS_BASE_FLOATS (O_PWH + NODE_BLOCKS)

__device__ __forceinline__ float leaky(float x) { return x >= 0.f ? x : 0.5f * x; }

// ---------------------------------------------------------------------------
// K1: grid-stride node kernel. 260 blocks x 256; 40 nodes per block.
// wh -> LDS + ws; hx(+b1), hy -> ws; per-BLOCK wh-sum partial.
// ---------------------------------------------------------------------------
__global__ __launch_bounds__(256)
void node_kernel(const float* __restrict__ x,
                 const float* __restrict__ wW, const float* __restrict__ wb,
                 const float* __restrict__ A1, const float* __restrict__ b1,
                 float* __restrict__ ws)
{
    __shared__ float s_wh[NPB][Sdim];
    __shared__ float s_r[4];
    const int tid = threadIdx.x;
    const int base = blockIdx.x * NPB;

    float v = 0.f;  // wh partial
    // wh: 40*12 = 480 elems
    #pragma unroll
    for (int rep = 0; rep < 2; rep++) {
        const int e = tid + rep * 256;
        if (e < NPB * Sdim) {
            const int n = e / Sdim, s = e - n * Sdim;
            const float* xr = x + (size_t)(base + n) * Sdim;
            float acc = wb[s];
            #pragma unroll
            for (int i = 0; i < Sdim; i++) acc += xr[i] * wW[i * Sdim + s];
            acc = leaky(acc);
            s_wh[n][s] = acc;
            ws[O_WH + (size_t)(base + n) * Sdim + s] = acc;
            v += acc;
        }
    }
    __syncthreads();

    // hx/hy: 40*96 = 3840 elems
    #pragma unroll
    for (int rep = 0; rep < 15; rep++) {
        const int e = tid + rep * 256;
        const int n = e / 96, r = e - n * 96;
        const int which = r / Hdim, d = r - which * Hdim;
        const float4 w0 = *(const float4*)&s_wh[n][0];
        const float4 w1 = *(const float4*)&s_wh[n][4];
        const float4 w2 = *(const float4*)&s_wh[n][8];
        const float* Ac = A1 + (which * Sdim) * Hdim + d;  // stride Hdim over s
        float acc = which ? 0.f : b1[d];                   // fold a1_b into hx
        acc += w0.x*Ac[0*Hdim] + w0.y*Ac[1*Hdim] + w0.z*Ac[2*Hdim] + w0.w*Ac[3*Hdim]
             + w1.x*Ac[4*Hdim] + w1.y*Ac[5*Hdim] + w1.z*Ac[6*Hdim] + w1.w*Ac[7*Hdim]
             + w2.x*Ac[8*Hdim] + w2.y*Ac[9*Hdim] + w2.z*Ac[10*Hdim] + w2.w*Ac[11*Hdim];
        ws[(which ? O_HY : O_HX) + (size_t)(base + n) * Hdim + d] = acc;
    }

    // block-reduce wh partial
    #pragma unroll
    for (int off = 32; off > 0; off >>= 1) v += __shfl_down(v, off);
    if ((tid & 63) == 0) s_r[tid >> 6] = v;
    __syncthreads();
    if (tid == 0) ws[O_PWH + blockIdx.x] = s_r[0] + s_r[1] + s_r[2] + s_r[3];
}

// ---------------------------------------------------------------------------
// K2 (merged att+bn): 4 bn per 256-thread block.
// Phase 0: stage A2 (480 floats, contiguous) into LDS; one barrier.
// Phase 1: lanes 0..159 = 2 lanes per edge (80 edges): each half computes
//          24 d's of the logit dot from LDS A2 (<=2 distinct LDS addrs per
//          wave instr -> broadcast, free), shfl_xor combine, softmax on even
//          lane -> s_am. Lanes 160..255 gather the 240 whj float4s.
// Phase 2 (after 2nd barrier): wave-synchronous tail (invn || einsum),
//          190-pair symmetric loss, block partials. No fences/global atomics.
// ---------------------------------------------------------------------------
__global__ __launch_bounds__(256)
void mega_kernel(const int* __restrict__ topk,
                 const float* __restrict__ A2, const float* __restrict__ b2,
                 float* __restrict__ ws, float* __restrict__ out)
{
    __shared__ float s_A2  [Hdim * Cdim];   // 480 floats, contiguous d*10+c
    __shared__ float s_whj [4][Kdim][12];   // 48B rows, float4-aligned
    __shared__ float s_am  [4][Kdim][12];   // probs, c padded with zeros
    __shared__ float s_invn[4][Kdim];
    __shared__ float s_red[2][4];

    const int tid = threadIdx.x;
    const int slot = tid >> 6, t = tid & 63;

    // ---- phase 0: stage A2 (120 float4) ----
    if (tid < 120) *(float4*)&s_A2[tid * 4] = *(const float4*)&A2[tid * 4];
    __syncthreads();

    if (tid < 160) {
        // ---- edge pair lanes: e = tid>>1, half = tid&1, 24 d's each ----
        const int e = tid >> 1, half = tid & 1;
        const int gid = blockIdx.x * 80 + e;
        const int bn_e = gid / Kdim;
        const int b_e  = bn_e / Ndim;
        const int j    = topk[gid];
        const int ek   = e / 20, kk = e - ek * 20;   // (slot, k) of this edge

        const float4* hx4 = (const float4*)(ws + O_HX + (size_t)bn_e * Hdim) + half * 6;
        const float4* hy4 = (const float4*)(ws + O_HY + ((size_t)b_e * Ndim + j) * Hdim) + half * 6;

        float acc[Cdim];
        #pragma unroll
        for (int c = 0; c < Cdim; c++) acc[c] = 0.f;
        #pragma unroll
        for (int q = 0; q < 6; q++) {
            const float4 xv = hx4[q], yv = hy4[q];
            const float hh[4] = { leaky(xv.x + yv.x), leaky(xv.y + yv.y),
                                  leaky(xv.z + yv.z), leaky(xv.w + yv.w) };
            #pragma unroll
            for (int i = 0; i < 4; i++) {
                const int d = half * 24 + q * 4 + i;
                #pragma unroll
                for (int c = 0; c < Cdim; c++)
                    acc[c] += hh[i] * s_A2[d * Cdim + c];
            }
        }
        float full[Cdim];
        #pragma unroll
        for (int c = 0; c < Cdim; c++) full[c] = acc[c] + __shfl_xor(acc[c], 1);
        if (half == 0) {
            float m = -1e30f;
            #pragma unroll
            for (int c = 0; c < Cdim; c++) { full[c] = leaky(full[c] + b2[c]); m = fmaxf(m, full[c]); }
            float sum = 0.f;
            #pragma unroll
            for (int c = 0; c < Cdim; c++) { full[c] = __expf(full[c] - m); sum += full[c]; }
            const float inv = 1.f / sum;
            *(float4*)&s_am[ek][kk][0] = make_float4(full[0]*inv, full[1]*inv, full[2]*inv, full[3]*inv);
            *(float4*)&s_am[ek][kk][4] = make_float4(full[4]*inv, full[5]*inv, full[6]*inv, full[7]*inv);
            *(float4*)&s_am[ek][kk][8] = make_float4(full[8]*inv, full[9]*inv, 0.f, 0.f);
        }
    } else {
        // ---- gather lanes (96): 240 float4s of whj ----
        for (int i = tid - 160; i < 240; i += 96) {
            const int kf = i / 3, q = i - kf * 3;          // kf in [0,80)
            const int sl = kf / 20, k = kf - sl * 20;
            const int gidx = blockIdx.x * 80 + kf;
            const int bn_i = gidx / Kdim;
            const int b_i  = bn_i / Ndim;
            const int j    = topk[gidx];
            const float4 v = *(const float4*)(ws + O_WH + ((size_t)b_i * Ndim + j) * Sdim + q * 4);
            *(float4*)&s_whj[sl][k][q * 4] = v;
        }
    }
    __syncthreads();

    const int bn = blockIdx.x * 4 + slot;
    float cl = 0.f, ds = 0.f;

    if (t < Kdim) {
        // per-k norm factor + diagonal dist contribution
        const float4 w0 = *(const float4*)&s_whj[slot][t][0];
        const float4 w1 = *(const float4*)&s_whj[slot][t][4];
        const float4 w2 = *(const float4*)&s_whj[slot][t][8];
        const float nn = w0.x*w0.x + w0.y*w0.y + w0.z*w0.z + w0.w*w0.w
                       + w1.x*w1.x + w1.y*w1.y + w1.z*w1.z + w1.w*w1.w
                       + w2.x*w2.x + w2.y*w2.y + w2.z*w2.z + w2.w*w2.w;
        const float invn = 1.f / (sqrtf(nn) + 1e-8f);
        s_invn[slot][t] = invn;
        ds += nn * invn * invn;               // dist_mat diagonal term
    } else if (t < Kdim + 30) {
        // output einsum: lane = (c, s-quad), float4 stores
        const int e = t - Kdim, c = e / 3, sq = e - c * 3;
        float4 o = make_float4(0.f, 0.f, 0.f, 0.f);
        #pragma unroll
        for (int k = 0; k < Kdim; k++) {
            const float a = s_am[slot][k][c];
            const float4 w = *(const float4*)&s_whj[slot][k][sq * 4];
            o.x += a * w.x; o.y += a * w.y; o.z += a * w.z; o.w += a * w.w;
        }
        *(float4*)(out + (size_t)bn * (Cdim * Sdim) + c * Sdim + sq * 4) = o;
    }
    __builtin_amdgcn_wave_barrier();         // invn -> loss is intra-wave

    // loss: 190 upper-triangle pairs, doubled (dist/prob are symmetric)
    #pragma unroll
    for (int it = 0; it < 3; it++) {
        const int e = t + it * 64;
        if (e < Tpairs) {
            const int r = Tpairs - 1 - e;
            const int m = (int)((sqrtf((float)(8 * r + 1)) - 1.f) * 0.5f + 1e-4f);
            const int k = Kdim - 2 - m;
            const int l = Kdim - 1 - (r - (m * (m + 1)) / 2);

            const float4 a0 = *(const float4*)&s_whj[slot][k][0];
            const float4 a1 = *(const float4*)&s_whj[slot][k][4];
            const float4 a2 = *(const float4*)&s_whj[slot][k][8];
            const float4 c0 = *(const float4*)&s_whj[slot][l][0];
            const float4 c1 = *(const float4*)&s_whj[slot][l][4];
            const float4 c2 = *(const float4*)&s_whj[slot][l][8];
            const float draw = a0.x*c0.x + a0.y*c0.y + a0.z*c0.z + a0.w*c0.w
                             + a1.x*c1.x + a1.y*c1.y + a1.z*c1.z + a1.w*c1.w
                             + a2.x*c2.x + a2.y*c2.y + a2.z*c2.z + a2.w*c2.w;
            const float d = draw * s_invn[slot][k] * s_invn[slot][l];

            const float4 p0 = *(const float4*)&s_am[slot][k][0];
            const float4 p1 = *(const float4*)&s_am[slot][k][4];
            const float4 p2 = *(const float4*)&s_am[slot][k][8];
            const float4 q0 = *(const float4*)&s_am[slot][l][0];
            const float4 q1 = *(const float4*)&s_am[slot][l][4];
            const float4 q2 = *(const float4*)&s_am[slot][l][8];
            float p = p0.x*q0.x + p0.y*q0.y + p0.z*q0.z + p0.w*q0.w
                    + p1.x*q1.x + p1.y*q1.y + p1.z*q1.z + p1.w*q1.w
                    + p2.x*q2.x + p2.y*q2.y + p2.z*q2.z + p2.w*q2.w;

            p = fminf(fmaxf(p, 1e-4f), 1.f - 1e-4f);
            const float lp = __logf(p);
            ds += 2.f * d;
            cl += 2.f * ((d >= 0.5f) ? -lp : lp);
        }
    }

    // wave reduce, then cross-slot reduce -> one block partial (plain stores)
    #pragma unroll
    for (int off = 32; off > 0; off >>= 1) {
        cl += __shfl_down(cl, off);
        ds += __shfl_down(ds, off);
    }
    if (t == 0) { s_red[0][slot] = cl; s_red[1][slot] = ds; }
    __syncthreads();
    if (tid == 0) {
        ws[O_PCL + blockIdx.x] = s_red[0][0] + s_red[0][1] + s_red[0][2] + s_red[0][3];
        ws[O_PDS + blockIdx.x] = s_red[1][0] + s_red[1][1] + s_red[1][2] + s_red[1][3];
    }
}

// ---------------------------------------------------------------------------
// K3: reduce partials -> 3 output scalars (tiny)
// ---------------------------------------------------------------------------
__global__ __launch_bounds__(1024)
void finalize(const float* __restrict__ ws, float* __restrict__ out)
{
    const int t = threadIdx.x;
    float cl = 0.f, ds = 0.f, wm = 0.f;
    for (int i = t; i < BN_BLOCKS; i += 1024) {
        cl += ws[O_PCL + i]; ds += ws[O_PDS + i];
    }
    if (t < NODE_BLOCKS) wm = ws[O_PWH + t];
    #pragma unroll
    for (int off = 32; off > 0; off >>= 1) {
        cl += __shfl_down(cl, off);
        ds += __shfl_down(ds, off);
        wm += __shfl_down(wm, off);
    }
    __shared__ float r[3][16];
    const int w = t >> 6, lane = t & 63;
    if (lane == 0) { r[0][w] = cl; r[1][w] = ds; r[2][w] = wm; }
    __syncthreads();
    if (t == 0) {
        float c = 0.f, d = 0.f, m = 0.f;
        #pragma unroll
        for (int i = 0; i < 16; i++) { c += r[0][i]; d += r[1][i]; m += r[2][i]; }
        out[OUT_SCALARS + 0] = c * (1.f / (float)NB);
        out[OUT_SCALARS + 1] = d * (1.f / ((float)NB * Kdim * Kdim));
        out[OUT_SCALARS + 2] = m * (1.f / ((float)NB * Sdim));
    }
}

// ---------------------------------------------------------------------------
// Fallback: round-1 monolithic kernel (used only if ws is too small)
// ---------------------------------------------------------------------------
__global__ void zero_scalars(float* out) {
    const int t = threadIdx.x;
    if (t < 3) out[OUT_SCALARS + t] = 0.f;
}

__global__ __launch_bounds__(64)
void fused_kernel(const float* __restrict__ input_data,
                  const float* __restrict__ w_W,  const float* __restrict__ w_b,
                  const float* __restrict__ a1_W, const float* __restrict__ a1_b,
                  const float* __restrict__ a2_W, const float* __restrict__ a2_b,
                  const int*   __restrict__ topk,
                  float* __restrict__ out)
{
    __shared__ float s_wW[Sdim * Sdim];
    __shared__ float s_wb[Sdim];
    __shared__ float s_A1[2 * Sdim * Hdim];
    __shared__ float s_b1[Hdim];
    __shared__ float s_A2f[Hdim * Cdim];
    __shared__ float s_b2f[Cdim];
    __shared__ float s_whs[Sdim];
    __shared__ float s_hx[Hdim];
    __shared__ float s_whj[Kdim][Sdim + 1];
    __shared__ float s_hid[Kdim][Hdim + 1];
    __shared__ float s_am [Kdim][Cdim + 1];
    __shared__ float s_wtn[Kdim][Sdim + 1];
    __shared__ int   s_idx[Kdim];

    const int t = threadIdx.x, bn = blockIdx.x, b = bn / Ndim;

    for (int i = t; i < Sdim * Sdim; i += 64)      s_wW[i] = w_W[i];
    if (t < Sdim)                                  s_wb[t] = w_b[t];
    for (int i = t; i < 2 * Sdim * Hdim; i += 64)  s_A1[i] = a1_W[i];
    if (t < Hdim)                                  s_b1[t] = a1_b[t];
    for (int i = t; i < Hdim * Cdim; i += 64)      s_A2f[i] = a2_W[i];
    if (t < Cdim)                                  s_b2f[t] = a2_b[t];
    if (t < Kdim)                                  s_idx[t] = topk[(size_t)bn * Kdim + t];
    __syncthreads();

    const float* xs = input_data + (size_t)bn * Sdim;
    if (t < Sdim) {
        float acc = s_wb[t];
        #pragma unroll
        for (int i = 0; i < Sdim; i++) acc += xs[i] * s_wW[i * Sdim + t];
        s_whs[t] = leaky(acc);
    }
    __syncthreads();

    if (t < Hdim) {
        float acc = 0.f;
        #pragma unroll
        for (int s = 0; s < Sdim; s++) acc += s_whs[s] * s_A1[s * Hdim + t];
        s_hx[t] = acc;
    }
    for (int e = t; e < Kdim * Sdim; e += 64) {
        const int k = e / Sdim, ss = e - k * Sdim;
        const float* xj = input_data + ((size_t)b * Ndim + s_idx[k]) * Sdim;
        float acc = s_wb[ss];
        #pragma unroll
        for (int i = 0; i < Sdim; i++) acc += xj[i] * s_wW[i * Sdim + ss];
        s_whj[k][ss] = leaky(acc);
    }
    __syncthreads();

    for (int e = t; e < Kdim * Hdim; e += 64) {
        const int k = e / Hdim, d = e - k * Hdim;
        float acc = s_hx[d] + s_b1[d];
        #pragma unroll
        for (int s = 0; s < Sdim; s++) acc += s_whj[k][s] * s_A1[(Sdim + s) * Hdim + d];
        s_hid[k][d] = leaky(acc);
    }
    __syncthreads();

    for (int e = t; e < Kdim * Cdim; e += 64) {
        const int k = e / Cdim, c = e - k * Cdim;
        float acc = s_b2f[c];
        #pragma unroll
        for (int d = 0; d < Hdim; d++) acc += s_hid[k][d] * s_A2f[d * Cdim + c];
        s_am[k][c] = leaky(acc);
    }
    __syncthreads();

    if (t < Kdim) {
        float m = -1e30f;
        #pragma unroll
        for (int c = 0; c < Cdim; c++) m = fmaxf(m, s_am[t][c]);
        float ex[Cdim]; float sum = 0.f;
        #pragma unroll
        for (int c = 0; c < Cdim; c++) { ex[c] = expf(s_am[t][c] - m); sum += ex[c]; }
        const float inv = 1.f / sum;
        #pragma unroll
        for (int c = 0; c < Cdim; c++) s_am[t][c] = ex[c] * inv;
        float nn = 0.f;
        #pragma unroll
        for (int s = 0; s < Sdim; s++) nn += s_whj[t][s] * s_whj[t][s];
        const float invn = 1.f / (sqrtf(nn) + 1e-8f);
        #pragma unroll
        for (int s = 0; s < Sdim; s++) s_wtn[t][s] = s_whj[t][s] * invn;
    }
    __syncthreads();

    float* op = out + (size_t)bn * (Cdim * Sdim);
    for (int e = t; e < Cdim * Sdim; e += 64) {
        const int c = e / Sdim, ss = e - c * Sdim;
        float acc = 0.f;
        #pragma unroll
        for (int k = 0; k < Kdim; k++) acc += s_am[k][c] * s_whj[k][ss];
        op[e] = acc;
    }

    float cl = 0.f, ds = 0.f;
    for (int e = t; e < Kdim * Kdim; e += 64) {
        const int k = e / Kdim, l = e - k * Kdim;
        float d = 0.f;
        #pragma unroll
        for (int s = 0; s < Sdim; s++) d += s_wtn[k][s] * s_wtn[l][s];
        ds += d;
        if (k != l) {
            float p = 0.f;
            #pragma unroll
            for (int c = 0; c < Cdim; c++) p += s_am[k][c] * s_am[l][c];
            p = fminf(fmaxf(p, 1e-4f), 1.f - 1e-4f);
            const float lp = logf(p);
            cl += (d >= 0.5f) ? -lp : lp;
        }
    }
    float whl = (t < Sdim) ? s_whs[t] : 0.f;
    #pragma unroll
    for (int off = 32; off > 0; off >>= 1) {
        cl  += __shfl_down(cl,  off);
        ds  += __shfl_down(ds,  off);
        whl += __shfl_down(whl, off);
    }
    if (t == 0) {
        atomicAdd(&out[OUT_SCALARS + 0], cl  * (1.f / (float)NB));
        atomicAdd(&out[OUT_SCALARS + 1], ds  * (1.f / ((float)NB * Kdim * Kdim)));
        atomicAdd(&out[OUT_SCALARS + 2], whl * (1.f / ((float)NB * Sdim)));
    }
}

extern "C" void kernel_launch(void* const* d_in, const int* in_sizes, int n_in,
                              void* d_out, int out_size, void* d_ws, size_t ws_size,
                              hipStream_t stream) {
    (void)in_sizes; (void)n_in; (void)out_size;
    // 0=fushed_features(unused), 1=input_data, 2=w_W, 3=w_b, 4=a1_W, 5=a1_b,
    // 6=a2_W, 7=a2_b, 8=adj_mx_topk_index
    const float* input_data = (const float*)d_in[1];
    const float* w_W  = (const float*)d_in[2];
    const float* w_b  = (const float*)d_in[3];
    const float* a1_W = (const float*)d_in[4];
    const float* a1_b = (const float*)d_in[5];
    const float* a2_W = (const float*)d_in[6];
    const float* a2_b = (const float*)d_in[7];
    const int*   topk = (const int*)d_in[8];
    float* out = (float*)d_out;
    float* ws  = (float*)d_ws;

    if (ws_size >= (size_t)WS_BASE_FLOATS * sizeof(float)) {
        hipLaunchKernelGGL(node_kernel, dim3(NODE_BLOCKS), dim3(256), 0, stream,
                           input_data, w_W, w_b, a1_W, a1_b, ws);
        hipLaunchKernelGGL(mega_kernel, dim3(BN_BLOCKS), dim3(256), 0, stream,
                           topk, a2_W, a2_b, ws, out);
        hipLaunchKernelGGL(finalize, dim3(1), dim3(1024), 0, stream, ws, out);
    } else {
        hipLaunchKernelGGL(zero_scalars, dim3(1), dim3(64), 0, stream, out);
        hipLaunchKernelGGL(fused_kernel, dim3(NB), dim3(64), 0, stream,
                           input_data, w_W, w_b, a1_W, a1_b, a2_W, a2_b, topk, out);
    }
}